// Round 5
// baseline (32.334 us; speedup 1.0000x reference)
//
#include <hip/hip_runtime.h>

typedef unsigned long long u64;
typedef unsigned int u32;

#define NB 64      // batch of graphs
#define NN 128     // nodes per graph
#define NITER 5
#define NGEN 6     // initial labels + 5 WL iterations
#define SALT 0xD1B54A32D192ED03ULL
#define NPAIR_OFF (NB*(NB-1)/2)  // 2016 strict lower-triangular pairs
#define TSLOTS 256               // hash table slots per (graph,gen)

__device__ __forceinline__ u64 mix64(u64 x) {
    u64 z = x + 0x9E3779B97F4A7C15ULL;
    z = (z ^ (z >> 30)) * 0xBF58476D1CE4E5B9ULL;
    z = (z ^ (z >> 27)) * 0x94D049BB133111EBULL;
    return z ^ (z >> 31);
}

// Insert key into 256-slot open-addressing table (LDS). Slots: {key, count}.
// key==0 marks empty; labels are splitmix64 outputs -> low 8 bits are the hash.
__device__ __forceinline__ void tab_insert(ulonglong2* tab, u64 key) {
    u32 s = (u32)key & (TSLOTS - 1);
    for (;;) {
        u64 old = atomicCAS((unsigned long long*)&tab[s].x, 0ULL, key);
        if (old == 0ULL || old == key) {
            atomicAdd((unsigned long long*)&tab[s].y, 1ULL);
            return;
        }
        s = (s + 1) & (TSLOTS - 1);
    }
}

// One block per graph, 512 threads (8 waves).
// 1) pack adjacency into 128-bit row masks (coalesced loads + ballot)
// 2) 5 WL iterations in LDS; per-gen label histogram built as a hash table
// 3) tables -> global; Kdiag[b] = sum over slots of count^2; out[b][b] = 1
// hgen layout: [b][gen][node] (768 u64 contiguous per graph).
__global__ __launch_bounds__(512) void wl_propagate(const float* __restrict__ adj,
                                                    const int* __restrict__ labels,
                                                    u64* __restrict__ hgen,
                                                    ulonglong2* __restrict__ tabg,
                                                    float* __restrict__ Kdiag,
                                                    float* __restrict__ out) {
    const int b = blockIdx.x;
    const int t = threadIdx.x;
    const int wave = t >> 6;   // 0..7
    const int lane = t & 63;

    __shared__ u64 bits_sh[NN][2];
    __shared__ u64 h_sh[NN];
    __shared__ u64 g_sh[NN];
    __shared__ u64 psum[4][NN];
    __shared__ ulonglong2 tab[NGEN][TSLOTS];  // 24 KiB
    __shared__ u32 part[8];

    // ---- pack adjacency: wave w handles rows w*16 .. w*16+15 ----
    const float* abase = adj + (size_t)b * NN * NN;
    #pragma unroll
    for (int k = 0; k < 16; ++k) {
        const int row = wave * 16 + k;
        const float* arow = abase + (size_t)row * NN;
        u64 m0 = __ballot(arow[lane] > 0.5f);
        u64 m1 = __ballot(arow[64 + lane] > 0.5f);
        if (lane == 0) { bits_sh[row][0] = m0; bits_sh[row][1] = m1; }
    }

    // ---- zero tables: 1536 slots / 512 threads = 3 each ----
    {
        ulonglong2* tf = &tab[0][0];
        #pragma unroll
        for (int k = 0; k < 3; ++k) tf[t + 512 * k] = make_ulonglong2(0ULL, 0ULL);
    }

    if (t < NN) {
        u64 h = mix64((u64)(unsigned)labels[b * NN + t]);
        h_sh[t] = h;
        hgen[(size_t)b * (NGEN * NN) + t] = h;
    }
    __syncthreads();

    if (t < NN) tab_insert(tab[0], h_sh[t]);

    for (int it = 0; it < NITER; ++it) {
        if (t < NN) g_sh[t] = mix64(h_sh[t] ^ SALT);
        __syncthreads();
        {   // 4 threads per node, each owns a 32-bit quarter of the mask
            const int i = t & 127;
            const int q = t >> 7;  // 0..3
            u32 m = (u32)(bits_sh[i][q >> 1] >> ((q & 1) * 32));
            const u64* gp = g_sh + q * 32;
            u64 s = 0;
            while (m) {
                int j = __builtin_ctz(m);
                m &= m - 1;
                s += gp[j];
            }
            psum[q][i] = s;
        }
        __syncthreads();
        if (t < NN) {
            u64 hn = mix64(mix64(h_sh[t]) + psum[0][t] + psum[1][t] + psum[2][t] + psum[3][t]);
            h_sh[t] = hn;
            hgen[(size_t)b * (NGEN * NN) + (it + 1) * NN + t] = hn;
            tab_insert(tab[it + 1], hn);
        }
        __syncthreads();
    }

    // ---- export tables + diagonal = sum over slots of count^2 ----
    {
        const ulonglong2* tf = &tab[0][0];
        ulonglong2* tg = tabg + (size_t)b * (NGEN * TSLOTS);
        u32 acc = 0;
        #pragma unroll
        for (int k = 0; k < 3; ++k) {
            const ulonglong2 v = tf[t + 512 * k];
            tg[t + 512 * k] = v;
            const u32 c = (u32)v.y;
            acc += c * c;
        }
        #pragma unroll
        for (int off = 32; off > 0; off >>= 1) acc += __shfl_down(acc, off);
        if (lane == 0) part[wave] = acc;
        __syncthreads();
        if (t == 0) {
            u32 d = 0;
            #pragma unroll
            for (int w = 0; w < 8; ++w) d += part[w];
            Kdiag[b] = (float)d;
            out[b * NB + b] = 1.0f;
        }
    }
}

// One block per strict lower pair (b1>b2), 256 threads.
// Stage b2's 6 hash tables (24 KiB) into LDS, then probe with b1's 768 labels
// (3 per thread, coalesced global reads): K[b1,b2] = sum of matched counts.
__global__ __launch_bounds__(256) void wl_pairs(const u64* __restrict__ hgen,
                                                const ulonglong2* __restrict__ tabg,
                                                const float* __restrict__ Kdiag,
                                                float* __restrict__ out) {
    const int p = blockIdx.x;
    // decode p -> (b1,b2), p = b1*(b1-1)/2 + b2, 0 <= b2 < b1
    int b1 = (int)((1.0f + sqrtf(1.0f + 8.0f * (float)p)) * 0.5f);
    while (b1 * (b1 - 1) / 2 > p) --b1;
    while ((b1 + 1) * b1 / 2 <= p) ++b1;
    const int b2 = p - b1 * (b1 - 1) / 2;

    const int t = threadIdx.x;
    __shared__ ulonglong2 tab[NGEN * TSLOTS];  // 24 KiB

    // stage b2's tables: 1536 x 16B over 256 threads, coalesced
    {
        const ulonglong2* src = tabg + (size_t)b2 * (NGEN * TSLOTS);
        #pragma unroll
        for (int k = 0; k < 6; ++k) tab[t + 256 * k] = src[t + 256 * k];
    }
    __syncthreads();

    u32 cnt = 0;
    const u64* abase = hgen + (size_t)b1 * (NGEN * NN);
    #pragma unroll
    for (int k = 0; k < 3; ++k) {
        const int idx = t + 256 * k;       // 0..767 -> gen = idx>>7
        const u64 a = abase[idx];
        const ulonglong2* tg = tab + (idx >> 7) * TSLOTS;
        u32 s = (u32)a & (TSLOTS - 1);
        for (;;) {
            const ulonglong2 v = tg[s];
            if (v.x == a) { cnt += (u32)v.y; break; }
            if (v.x == 0ULL) break;
            s = (s + 1) & (TSLOTS - 1);
        }
    }

    #pragma unroll
    for (int off = 32; off > 0; off >>= 1) cnt += __shfl_down(cnt, off);
    __shared__ u32 part[4];
    if ((t & 63) == 0) part[t >> 6] = cnt;
    __syncthreads();
    if (t == 0) {
        const float v = (float)(part[0] + part[1] + part[2] + part[3])
                      / (sqrtf(Kdiag[b1]) * sqrtf(Kdiag[b2]));
        out[b1 * NB + b2] = v;
        out[b2 * NB + b1] = v;
    }
}

extern "C" void kernel_launch(void* const* d_in, const int* in_sizes, int n_in,
                              void* d_out, int out_size, void* d_ws, size_t ws_size,
                              hipStream_t stream) {
    const float* adj   = (const float*)d_in[0];   // [64,128,128] fp32 (0/1)
    const int*  labels = (const int*)d_in[1];     // [64,128] int32
    float* out = (float*)d_out;                   // [64,64] fp32

    char* ws = (char*)d_ws;
    u64*        hgen  = (u64*)ws;                          // 64*768*8  = 384 KiB
    float*      Kdiag = (float*)(ws + 448 * 1024);         // 256 B
    ulonglong2* tabg  = (ulonglong2*)(ws + 512 * 1024);    // 64*1536*16 = 1.5 MiB

    wl_propagate<<<NB, 512, 0, stream>>>(adj, labels, hgen, tabg, Kdiag, out);
    wl_pairs<<<NPAIR_OFF, 256, 0, stream>>>(hgen, tabg, Kdiag, out);
}